// Round 8
// baseline (27.303 us; speedup 1.0000x reference)
//
#include <hip/hip_runtime.h>
#include <math.h>

#define NELEM  8388608
#define GRID   2048
#define BLOCK  256
#define NVEC   (NELEM / 4)          // 2097152
#define STRIDE (GRID * BLOCK)       // 524288 -> exactly 4 vec4 groups per thread

// Two-kernel structure (R1/R6/R7-proven). Changes vs R7:
//  - lgammaf libcall ELIMINATED: ln(t!) and cumsum(ln(k!)) are computed with
//    one __logf + two block-wide inclusive scans (the quantities are exactly
//    scan(ln j) and scan(scan(ln j))) — removes ~hundreds of branchy VALU
//    cycles per thread from every block's preamble.
//  - partials stored as float, finalize reads them as float4 (one latency
//    round). Sum ~1.3e11, float partial rounding ~1e2 absolute -> loss error
//    ~1e-5 vs threshold 316.
__device__ __forceinline__ float block_incl_scan(float x, int lane, int wid,
                                                 volatile float* woff)
{
    float scan = x;
    #pragma unroll
    for (int d = 1; d < 64; d <<= 1) {
        float n = __shfl_up(scan, d, 64);
        if (lane >= d) scan += n;
    }
    if (lane == 63) woff[wid] = scan;
    __syncthreads();
    float off = 0.f;
    #pragma unroll
    for (int w = 0; w < 4; ++w) off += (w < wid) ? woff[w] : 0.f;
    return scan + off;
}

__global__ __launch_bounds__(BLOCK, 8) void loss_main(
    const float4* __restrict__ lam4,
    const int4*   __restrict__ tgt4,
    const int4*   __restrict__ risk4,
    float*        __restrict__ partials)
{
    __shared__ float  cst[512];     // cst[r*256 + t]
    __shared__ float  woff1[4];
    __shared__ float  woff2[4];
    __shared__ double wsum[4];

    const int tid  = threadIdx.x;
    const int lane = tid & 63;
    const int wid  = tid >> 6;
    const int base = blockIdx.x * BLOCK + tid;

    // ---- issue all 12 vector loads first (latency overlaps table build) ----
    float4 L0 = lam4[base];              int4 T0 = tgt4[base];              int4 R0 = risk4[base];
    float4 L1 = lam4[base + STRIDE];     int4 T1 = tgt4[base + STRIDE];     int4 R1 = risk4[base + STRIDE];
    float4 L2 = lam4[base + 2 * STRIDE]; int4 T2 = tgt4[base + 2 * STRIDE]; int4 R2 = risk4[base + 2 * STRIDE];
    float4 L3 = lam4[base + 3 * STRIDE]; int4 T3 = tgt4[base + 3 * STRIDE]; int4 R3 = risk4[base + 3 * STRIDE];

    // ---- table via double scan: lnfact = scan(ln j), csum = scan(lnfact) ----
    {
        float tf = (float)tid;
        float x  = (tid == 0) ? 0.0f : __logf(tf);
        float lnfact = block_incl_scan(x, lane, wid, woff1);      // ln(tid!)
        float csum   = block_incl_scan(lnfact, lane, wid, woff2); // sum ln(k!), k<=tid
        cst[tid]       = (tf + 1.0f) + csum;  // r=0 constant term
        cst[256 + tid] = -lnfact;             // r=1 constant term
    }
    __syncthreads();

    // ---- per element: val = a*la + b*ll + cst[r*256+t]
    //      a = r ? -1 : t+1 ;  b = r ? t : -t(t+1)/2  (VALU, no gather) ----
    double acc = 0.0;
    #define ONE(la_, t_, r_, g_) {                                   \
        float  la = (la_);                                           \
        int    t  = (t_);                                            \
        int    r  = (r_);                                            \
        float  tf = (float)t;                                        \
        float  a  = r ? -1.0f : (tf + 1.0f);                         \
        float  tt = fmaf(tf, tf, tf);       /* t(t+1) */             \
        float  b  = r ? tf : -0.5f * tt;                             \
        float  cc = cst[(r << 8) | t];                               \
        float  ll = __logf(la);                                      \
        g_ += fmaf(a, la, fmaf(b, ll, cc));                          \
    }
    #define GROUP(L, T, R) {                                         \
        float g = 0.f;                                               \
        ONE(L.x, T.x, R.x, g);                                       \
        ONE(L.y, T.y, R.y, g);                                       \
        ONE(L.z, T.z, R.z, g);                                       \
        ONE(L.w, T.w, R.w, g);                                       \
        acc += (double)g;                                            \
    }
    GROUP(L0, T0, R0);
    GROUP(L1, T1, R1);
    GROUP(L2, T2, R2);
    GROUP(L3, T3, R3);
    #undef GROUP
    #undef ONE

    // ---- block reduce (double, fixed order) ----
    #pragma unroll
    for (int d = 32; d > 0; d >>= 1) acc += __shfl_down(acc, d, 64);
    if (lane == 0) wsum[wid] = acc;
    __syncthreads();
    if (tid == 0)
        partials[blockIdx.x] = (float)(wsum[0] + wsum[1] + wsum[2] + wsum[3]);
}

__global__ __launch_bounds__(256) void loss_finalize(
    const float4* __restrict__ partials4, float* __restrict__ out)
{
    const int tid  = threadIdx.x;
    const int lane = tid & 63;
    const int wid  = tid >> 6;
    __shared__ double ws[4];

    // 2048 floats = 512 float4; 256 threads read 2 each (fixed order)
    float4 a = partials4[tid];
    float4 b = partials4[tid + 256];
    double acc = ((double)a.x + a.y) + ((double)a.z + a.w)
               + ((double)b.x + b.y) + ((double)b.z + b.w);
    #pragma unroll
    for (int d = 32; d > 0; d >>= 1) acc += __shfl_down(acc, d, 64);
    if (lane == 0) ws[wid] = acc;
    __syncthreads();
    if (tid == 0) {
        double s = ws[0] + ws[1] + ws[2] + ws[3];
        out[0] = (float)(-s / (double)NELEM);
    }
}

extern "C" void kernel_launch(void* const* d_in, const int* in_sizes, int n_in,
                              void* d_out, int out_size, void* d_ws, size_t ws_size,
                              hipStream_t stream)
{
    const float4* lam4  = (const float4*)d_in[0];
    const int4*   tgt4  = (const int4*)d_in[1];
    const int4*   risk4 = (const int4*)d_in[2];
    float* partials     = (float*)d_ws;   // 2048 floats; every slot written every call
    float* out          = (float*)d_out;

    loss_main<<<GRID, BLOCK, 0, stream>>>(lam4, tgt4, risk4, partials);
    loss_finalize<<<1, 256, 0, stream>>>((const float4*)partials, out);
}

// Round 9
// 24.656 us; speedup vs baseline: 1.1073x; 1.1073x over previous
//
#include <hip/hip_runtime.h>
#include <math.h>

#define NELEM  8388608
#define GRID   4096
#define BLOCK  256
#define NVEC   (NELEM / 4)          // 2097152
#define STRIDE (GRID * BLOCK)       // 1048576 -> exactly 2 vec4 groups per thread

// R7 structure (best: 24.25 us) with ONE change: GRID 2048->4096 (2 groups/
// thread instead of 4). More independent waves for latency hiding, smaller
// per-thread register footprint, smoother tail. Everything else identical.
__global__ __launch_bounds__(BLOCK, 8) void loss_main(
    const float4* __restrict__ lam4,
    const int4*   __restrict__ tgt4,
    const int4*   __restrict__ risk4,
    double*       __restrict__ partials)
{
    __shared__ float  cst[512];     // cst[r*256 + t]
    __shared__ float  woff[4];
    __shared__ double wsum[4];

    const int tid  = threadIdx.x;
    const int lane = tid & 63;
    const int wid  = tid >> 6;
    const int base = blockIdx.x * BLOCK + tid;

    // ---- issue all 6 vector loads first (latency overlaps table build) ----
    float4 L0 = lam4[base];          int4 T0 = tgt4[base];          int4 R0 = risk4[base];
    float4 L1 = lam4[base + STRIDE]; int4 T1 = tgt4[base + STRIDE]; int4 R1 = risk4[base + STRIDE];

    // ---- build constant-term table (one t per thread) ----
    {
        float tf = (float)tid;
        float v  = lgammaf(tf + 1.0f);       // ln(t!)
        float scan = v;                       // inclusive wave scan
        #pragma unroll
        for (int d = 1; d < 64; d <<= 1) {
            float n = __shfl_up(scan, d, 64);
            if (lane >= d) scan += n;
        }
        if (lane == 63) woff[wid] = scan;
        __syncthreads();
        float off = 0.f;
        for (int w = 0; w < wid; ++w) off += woff[w];
        float csum = scan + off;              // cumsum of ln(k!) up to t
        cst[tid]       = (tf + 1.0f) + csum;  // r=0: (t+1) + csum[t]
        cst[256 + tid] = -v;                  // r=1: -lgamma(t+1)
    }
    __syncthreads();

    // ---- per element: val = a*la + b*ll + cst[r*256+t]
    //      a = r ? -1 : t+1 ;  b = r ? t : -t(t+1)/2  (VALU, no gather) ----
    double acc = 0.0;
    #define ONE(la_, t_, r_, g_) {                                   \
        float  la = (la_);                                           \
        int    t  = (t_);                                            \
        int    r  = (r_);                                            \
        float  tf = (float)t;                                        \
        float  a  = r ? -1.0f : (tf + 1.0f);                         \
        float  tt = fmaf(tf, tf, tf);       /* t(t+1) */             \
        float  b  = r ? tf : -0.5f * tt;                             \
        float  cc = cst[(r << 8) | t];                               \
        float  ll = __logf(la);                                      \
        g_ += fmaf(a, la, fmaf(b, ll, cc));                          \
    }
    #define GROUP(L, T, R) {                                         \
        float g = 0.f;                                               \
        ONE(L.x, T.x, R.x, g);                                       \
        ONE(L.y, T.y, R.y, g);                                       \
        ONE(L.z, T.z, R.z, g);                                       \
        ONE(L.w, T.w, R.w, g);                                       \
        acc += (double)g;                                            \
    }
    GROUP(L0, T0, R0);
    GROUP(L1, T1, R1);
    #undef GROUP
    #undef ONE

    // ---- block reduce (double, fixed order) ----
    #pragma unroll
    for (int d = 32; d > 0; d >>= 1) acc += __shfl_down(acc, d, 64);
    if (lane == 0) wsum[wid] = acc;
    __syncthreads();
    if (tid == 0)
        partials[blockIdx.x] = wsum[0] + wsum[1] + wsum[2] + wsum[3];
}

__global__ __launch_bounds__(256) void loss_finalize(
    const double* __restrict__ partials, float* __restrict__ out)
{
    const int tid  = threadIdx.x;
    const int lane = tid & 63;
    const int wid  = tid >> 6;
    __shared__ double ws[4];

    double acc = 0.0;
    #pragma unroll
    for (int i = 0; i < GRID / 256; ++i)           // fixed index order
        acc += partials[tid + i * 256];
    #pragma unroll
    for (int d = 32; d > 0; d >>= 1) acc += __shfl_down(acc, d, 64);
    if (lane == 0) ws[wid] = acc;
    __syncthreads();
    if (tid == 0) {
        double s = ws[0] + ws[1] + ws[2] + ws[3];
        out[0] = (float)(-s / (double)NELEM);
    }
}

extern "C" void kernel_launch(void* const* d_in, const int* in_sizes, int n_in,
                              void* d_out, int out_size, void* d_ws, size_t ws_size,
                              hipStream_t stream)
{
    const float4* lam4  = (const float4*)d_in[0];
    const int4*   tgt4  = (const int4*)d_in[1];
    const int4*   risk4 = (const int4*)d_in[2];
    double* partials    = (double*)d_ws;   // 4096 * 8 B; every slot written every call
    float*  out         = (float*)d_out;

    loss_main<<<GRID, BLOCK, 0, stream>>>(lam4, tgt4, risk4, partials);
    loss_finalize<<<1, 256, 0, stream>>>(partials, out);
}